// Round 3
// baseline (8738.232 us; speedup 1.0000x reference)
//
#include <hip/hip_runtime.h>
#include <hip/hip_bf16.h>
#include <stdint.h>

// ---------------------------------------------------------------------------
// QLSTM: 2-layer LSTM, T=512, B=64, D=512, H=1024, fp32 in/out.
// R5: tag-validated dataflow. h exchanged as u32 words (tag16 | h_bf16<<16)
// in 8-deep rotating slot buffers. Producers: sc1 write-through stores (no
// drain, no flags, no barrier). Consumers: PLAIN CACHED loads (line-granular
// MALL->L2 fetch at full L2 BW); per-word tags validate freshness; stale
// words (rare: un-evicted 8-phase-old L2 lines, or consumer racing ahead of
// producer) are re-fetched via uncached per-granule retry. No buffer_inv,
// no grid barrier: blocks free-run, phase-locked by tags (skew<=1 among
// mutually-consuming peers). L0 gates its slot-overwrite on L1 progress
// >= p-4 (off critical path) to bound the one unbounded-skew case.
// Weights persist in VGPRs; out written with plain cached stores.
// ---------------------------------------------------------------------------

#define T_STEPS 512
#define BATCH   64
#define DIN     512
#define HID     1024
#define NBLK    256
#define NTHR    512

typedef __attribute__((ext_vector_type(8)))  short short8;   // 8 bf16
typedef __attribute__((ext_vector_type(16))) float f32x16;   // 32x32 acc

union S8U { unsigned u[4]; short8 v; };

// ---- workspace layout (bytes) ----
#define OFF_WIH0 ((size_t)0)          // 4 MB  bf16 [4096][512]
#define OFF_WHH0 ((size_t)4194304)    // 8 MB  bf16 [4096][1024]
#define OFF_WIH1 ((size_t)12582912)   // 8 MB
#define OFF_WHH1 ((size_t)20971520)   // 8 MB
#define OFF_XBF  ((size_t)29360128)   // 33.55 MB bf16 [512][64][512]
#define OFF_H0R  ((size_t)62914560)   // 2 MB: u32 tagged [8][64][1024]
#define OFF_H1R  ((size_t)(OFF_H0R + 2097152))   // 2 MB
#define OFF_PRG  ((size_t)(OFF_H1R + 2097152))   // 128 u32 L1-progress flags

// ---------------------------------------------------------------------------
__global__ void cvt_bf16x4(const float4* __restrict__ in,
                           ushort4* __restrict__ out, int n4) {
  int i = blockIdx.x * blockDim.x + threadIdx.x;
  if (i >= n4) return;
  float4 v = in[i];
  __hip_bfloat16 b0 = __float2bfloat16(v.x), b1 = __float2bfloat16(v.y),
                 b2 = __float2bfloat16(v.z), b3 = __float2bfloat16(v.w);
  ushort4 o;
  o.x = *(unsigned short*)&b0; o.y = *(unsigned short*)&b1;
  o.z = *(unsigned short*)&b2; o.w = *(unsigned short*)&b3;
  out[i] = o;
}

__device__ __forceinline__ float sigf(float x) {
  return 1.0f / (1.0f + __expf(-x));
}
__device__ __forceinline__ float tanhfast(float x) {
  return 1.0f - 2.0f / (__expf(2.0f * x) + 1.0f);
}

__device__ __forceinline__ bool tag_ok4(uint4 q, unsigned short t16) {
  return ((unsigned short)q.x == t16) & ((unsigned short)q.y == t16) &
         ((unsigned short)q.z == t16) & ((unsigned short)q.w == t16);
}

// Load one wave's 8 A-fragments (8 kk x 8 k-values) from a tagged slot.
// sb = slot_base + m*1024 + ksub (u32 units). First pass: plain cached
// dwordx4 (line-granular, L2-served). Stale granules: uncached retry.
__device__ __forceinline__ void load_tagged8(const unsigned* sb, int w,
                                             unsigned tg, short8 frag[8]) {
  const unsigned short t16 = (unsigned short)tg;
  uint4 wa[8], wb[8];
#pragma unroll
  for (int kk = 0; kk < 8; ++kk) {
    const unsigned* pk = sb + (size_t)(w + 8 * kk) * 16;
    asm volatile("global_load_dwordx4 %0, %1, off" : "=v"(wa[kk]) : "v"(pk) : "memory");
    asm volatile("global_load_dwordx4 %0, %1, off" : "=v"(wb[kk]) : "v"(pk + 4) : "memory");
  }
  asm volatile("s_waitcnt vmcnt(0)" ::: "memory");
#pragma unroll
  for (int kk = 0; kk < 8; ++kk) {
    const unsigned* pk = sb + (size_t)(w + 8 * kk) * 16;
    int tries = 0;
    while (!__all(tag_ok4(wa[kk], t16))) {         // rare slow path
      if (++tries > (1 << 22)) break;              // anti-hang bailout
      __builtin_amdgcn_s_sleep(2);
      asm volatile("global_load_dwordx4 %0, %1, off sc0 sc1"
                   : "=v"(wa[kk]) : "v"(pk) : "memory");
      asm volatile("s_waitcnt vmcnt(0)" ::: "memory");
    }
    tries = 0;
    while (!__all(tag_ok4(wb[kk], t16))) {
      if (++tries > (1 << 22)) break;
      __builtin_amdgcn_s_sleep(2);
      asm volatile("global_load_dwordx4 %0, %1, off sc0 sc1"
                   : "=v"(wb[kk]) : "v"(pk + 4) : "memory");
      asm volatile("s_waitcnt vmcnt(0)" ::: "memory");
    }
    S8U f;   // extract high halves: value i = word_i >> 16
    f.u[0] = __builtin_amdgcn_perm(wa[kk].y, wa[kk].x, 0x07060302);
    f.u[1] = __builtin_amdgcn_perm(wa[kk].w, wa[kk].z, 0x07060302);
    f.u[2] = __builtin_amdgcn_perm(wb[kk].y, wb[kk].x, 0x07060302);
    f.u[3] = __builtin_amdgcn_perm(wb[kk].w, wb[kk].z, 0x07060302);
    frag[kk] = f.v;
  }
}

// ---------------------------------------------------------------------------
__launch_bounds__(NTHR, 2)
__global__ void lstm_persist(const __hip_bfloat16* __restrict__ whh0,
                             const __hip_bfloat16* __restrict__ wih0,
                             const __hip_bfloat16* __restrict__ wih1,
                             const __hip_bfloat16* __restrict__ whh1,
                             const __hip_bfloat16* __restrict__ xbf,
                             unsigned* h0r, unsigned* h1r, unsigned* prog,
                             const float* __restrict__ bih0, const float* __restrict__ bhh0,
                             const float* __restrict__ bih1, const float* __restrict__ bhh1,
                             float* __restrict__ out) {
  __shared__ float dump[8][2][32][32];   // 64 KiB: 8 wave-partials x 2 tiles

  const int tid = threadIdx.x;
  const int w   = tid >> 6;        // wave 0..7 (K-split)
  const int l   = tid & 63;
  const int cu  = blockIdx.x;
  const bool L1cu = (cu >= 128);
  const int q  = L1cu ? (cu - 128) : cu;
  const int jt = q >> 1;           // 16-hidden-col granule
  const int mh = q & 1;            // 32-row batch half

  const int n    = l & 31;         // MFMA col (B) / row (A) within tile
  const int ksub = (l >> 5) * 8;   // A/B fragment k sub-offset
  const int m    = mh * 32 + n;    // batch row for A loads

  // elementwise identity
  const int erow = tid >> 4;           // 0..31
  const int ehc  = tid & 15;           // 0..15
  const int ecol = jt * 16 + ehc;
  const int em   = mh * 32 + erow;

  float bi, bf_, bg, bo;
  {
    const float* ba = L1cu ? bih1 : bih0;
    const float* bb = L1cu ? bhh1 : bhh0;
    bi  = ba[0 * HID + ecol] + bb[0 * HID + ecol];
    bf_ = ba[1 * HID + ecol] + bb[1 * HID + ecol];
    bg  = ba[2 * HID + ecol] + bb[2 * HID + ecol];
    bo  = ba[3 * HID + ecol] + bb[3 * HID + ecol];
  }
  float cst = 0.0f;

  // ---- one-time weight preload into registers ----
  const int wr0 = ((n >> 4) + 0) * HID + jt * 16 + (n & 15);
  const int wr1 = ((n >> 4) + 2) * HID + jt * 16 + (n & 15);

  short8 w1a[8], w1b[8];   // matmul1 (K=1024): L0=Whh0, L1=Wih1
  short8 w2a[8], w2b[8];   // matmul2: L0=Wih0 (K=512, 4 used), L1=Whh1 (K=1024)
  if (!L1cu) {
#pragma unroll
    for (int kk = 0; kk < 8; ++kk) {
      int k0 = (w + 8 * kk) * 16 + ksub;
      w1a[kk] = *(const short8*)(whh0 + (size_t)wr0 * 1024 + k0);
      w1b[kk] = *(const short8*)(whh0 + (size_t)wr1 * 1024 + k0);
    }
#pragma unroll
    for (int kk = 0; kk < 4; ++kk) {
      int k0 = (w + 8 * kk) * 16 + ksub;
      w2a[kk] = *(const short8*)(wih0 + (size_t)wr0 * 512 + k0);
      w2b[kk] = *(const short8*)(wih0 + (size_t)wr1 * 512 + k0);
    }
  } else {
#pragma unroll
    for (int kk = 0; kk < 8; ++kk) {
      int k0 = (w + 8 * kk) * 16 + ksub;
      w1a[kk] = *(const short8*)(wih1 + (size_t)wr0 * 1024 + k0);
      w1b[kk] = *(const short8*)(wih1 + (size_t)wr1 * 1024 + k0);
      w2a[kk] = *(const short8*)(whh1 + (size_t)wr0 * 1024 + k0);
      w2b[kk] = *(const short8*)(whh1 + (size_t)wr1 * 1024 + k0);
    }
  }

  if (!L1cu) {
    // ================= LAYER 0 blocks: phases p = 0..511 =================
    for (int p = 0; p < T_STEPS; ++p) {
      // issue L1-progress poll early (checked just before the h0 store)
      int progv = (int)__hip_atomic_load(prog + mh * 64 + l,
                                         __ATOMIC_RELAXED, __HIP_MEMORY_SCOPE_AGENT);

      f32x16 acc0, acc1;
#pragma unroll
      for (int r = 0; r < 16; ++r) { acc0[r] = 0.0f; acc1[r] = 0.0f; }

      // matmul1: h0_{p-1} @ Whh0^T, tagged slot (p-1)&7, tag p
      short8 a1[8];
      load_tagged8(h0r + (size_t)((p + 7) & 7) * 65536 + (size_t)m * 1024 + ksub,
                   w, (unsigned)p, a1);

      // matmul2 operand: x_p (read-only, plain cached)
      const short8* A2 = (const short8*)(xbf + ((size_t)p * 64 + m) * 512 + ksub);
      short8 a2[4];
#pragma unroll
      for (int kk = 0; kk < 4; ++kk) a2[kk] = A2[(w + 8 * kk) * 2];

#pragma unroll
      for (int kk = 0; kk < 8; ++kk) {
        acc0 = __builtin_amdgcn_mfma_f32_32x32x16_bf16(a1[kk], w1a[kk], acc0, 0, 0, 0);
        acc1 = __builtin_amdgcn_mfma_f32_32x32x16_bf16(a1[kk], w1b[kk], acc1, 0, 0, 0);
      }
#pragma unroll
      for (int kk = 0; kk < 4; ++kk) {
        acc0 = __builtin_amdgcn_mfma_f32_32x32x16_bf16(a2[kk], w2a[kk], acc0, 0, 0, 0);
        acc1 = __builtin_amdgcn_mfma_f32_32x32x16_bf16(a2[kk], w2b[kk], acc1, 0, 0, 0);
      }

      __syncthreads();
#pragma unroll
      for (int r = 0; r < 16; ++r) {
        int row = (r & 3) + 8 * (r >> 2) + 4 * (l >> 5);
        dump[w][0][row][n] = acc0[r];
        dump[w][1][row][n] = acc1[r];
      }
      __syncthreads();

      float gi = bi, gf = bf_, gg = bg, go = bo;
#pragma unroll
      for (int ww = 0; ww < 8; ++ww) {
        gi += dump[ww][0][erow][ehc];
        gf += dump[ww][0][erow][ehc + 16];
        gg += dump[ww][1][erow][ehc];
        go += dump[ww][1][erow][ehc + 16];
      }
      float si = sigf(gi), sf = sigf(gf), so = sigf(go);
      float tg = tanhfast(gg);
      cst = sf * cst + si * tg;
      float h = so * tanhfast(cst);

      // backpressure: don't overwrite slot p&7 (tag p-7) until L1 >= p-4
      {
        const int need = p - 4;
        int tries = 0;
        while (!__all(progv >= need)) {
          if (++tries > (1 << 22)) break;
          __builtin_amdgcn_s_sleep(8);
          progv = (int)__hip_atomic_load(prog + mh * 64 + l,
                                         __ATOMIC_RELAXED, __HIP_MEMORY_SCOPE_AGENT);
        }
      }

      // tagged h0 store: slot p&7, tag p+1 (sc1 write-through; no drain)
      {
        __hip_bfloat16 hbf = __float2bfloat16(h);
        unsigned word = ((unsigned)(p + 1) & 0xFFFFu) |
                        ((unsigned)*(const unsigned short*)&hbf << 16);
        __hip_atomic_store(h0r + (size_t)(p & 7) * 65536 + (size_t)em * 1024 + ecol,
                           word, __ATOMIC_RELAXED, __HIP_MEMORY_SCOPE_AGENT);
      }

      if (p == T_STEPS - 1) {   // final h0, c0 (plain cached stores)
        out[(size_t)T_STEPS * BATCH * HID + 0 * BATCH * HID + (size_t)em * HID + ecol] = h;
        out[(size_t)T_STEPS * BATCH * HID + 1 * BATCH * HID + (size_t)em * HID + ecol] = cst;
      }
    }
  } else {
    // ================= LAYER 1 blocks: phases p = 1..512 =================
    for (int p = 1; p <= T_STEPS; ++p) {
      f32x16 acc0, acc1;
#pragma unroll
      for (int r = 0; r < 16; ++r) { acc0[r] = 0.0f; acc1[r] = 0.0f; }

      // matmul1: h0_{p-1} @ Wih1^T, tagged slot (p-1)&7, tag p
      short8 a1[8];
      load_tagged8(h0r + (size_t)((p + 7) & 7) * 65536 + (size_t)m * 1024 + ksub,
                   w, (unsigned)p, a1);
#pragma unroll
      for (int kk = 0; kk < 8; ++kk) {
        acc0 = __builtin_amdgcn_mfma_f32_32x32x16_bf16(a1[kk], w1a[kk], acc0, 0, 0, 0);
        acc1 = __builtin_amdgcn_mfma_f32_32x32x16_bf16(a1[kk], w1b[kk], acc1, 0, 0, 0);
      }

      // matmul2: h1_{p-2} @ Whh1^T, tagged slot (p-1)&7, tag p (tag 0 at p=1)
      short8 a2[8];
      {
        unsigned tg1 = (p == 1) ? 0u : (unsigned)p;
        load_tagged8(h1r + (size_t)((p + 7) & 7) * 65536 + (size_t)m * 1024 + ksub,
                     w, tg1, a2);
      }
#pragma unroll
      for (int kk = 0; kk < 8; ++kk) {
        acc0 = __builtin_amdgcn_mfma_f32_32x32x16_bf16(a2[kk], w2a[kk], acc0, 0, 0, 0);
        acc1 = __builtin_amdgcn_mfma_f32_32x32x16_bf16(a2[kk], w2b[kk], acc1, 0, 0, 0);
      }

      __syncthreads();
#pragma unroll
      for (int r = 0; r < 16; ++r) {
        int row = (r & 3) + 8 * (r >> 2) + 4 * (l >> 5);
        dump[w][0][row][n] = acc0[r];
        dump[w][1][row][n] = acc1[r];
      }
      __syncthreads();

      float gi = bi, gf = bf_, gg = bg, go = bo;
#pragma unroll
      for (int ww = 0; ww < 8; ++ww) {
        gi += dump[ww][0][erow][ehc];
        gf += dump[ww][0][erow][ehc + 16];
        gg += dump[ww][1][erow][ehc];
        go += dump[ww][1][erow][ehc + 16];
      }
      float si = sigf(gi), sf = sigf(gf), so = sigf(go);
      float tg = tanhfast(gg);
      cst = sf * cst + si * tg;
      float h = so * tanhfast(cst);

      // tagged h1 store: slot p&7, tag p+1 (h1_511 never consumed -> skip)
      if (p <= T_STEPS - 1) {
        __hip_bfloat16 hbf = __float2bfloat16(h);
        unsigned word = ((unsigned)(p + 1) & 0xFFFFu) |
                        ((unsigned)*(const unsigned short*)&hbf << 16);
        __hip_atomic_store(h1r + (size_t)(p & 7) * 65536 + (size_t)em * 1024 + ecol,
                           word, __ATOMIC_RELAXED, __HIP_MEMORY_SCOPE_AGENT);
      }

      // progress flag: "finished reading phase-p inputs" (safe: past the
      // post-dump __syncthreads, so all 8 waves' loads were consumed)
      if (tid == 0)
        __hip_atomic_store(prog + mh * 64 + jt, (unsigned)p,
                           __ATOMIC_RELAXED, __HIP_MEMORY_SCOPE_AGENT);

      // outputs (plain cached stores; kernel-end writeback publishes them)
      out[((size_t)(p - 1) * BATCH + em) * HID + ecol] = h;   // sequence out
      if (p == T_STEPS) {       // final h1, c1
        out[(size_t)T_STEPS * BATCH * HID + 2 * BATCH * HID + (size_t)em * HID + ecol] = h;
        out[(size_t)T_STEPS * BATCH * HID + 3 * BATCH * HID + (size_t)em * HID + ecol] = cst;
      }
    }
  }
}

// ---------------------------------------------------------------------------
extern "C" void kernel_launch(void* const* d_in, const int* in_sizes, int n_in,
                              void* d_out, int out_size, void* d_ws, size_t ws_size,
                              hipStream_t stream) {
  const float* x     = (const float*)d_in[0];
  const float* Wih0  = (const float*)d_in[1];
  const float* Whh0  = (const float*)d_in[2];
  const float* b_ih0 = (const float*)d_in[3];
  const float* b_hh0 = (const float*)d_in[4];
  const float* Wih1  = (const float*)d_in[5];
  const float* Whh1  = (const float*)d_in[6];
  const float* b_ih1 = (const float*)d_in[7];
  const float* b_hh1 = (const float*)d_in[8];
  float* out = (float*)d_out;

  char* ws = (char*)d_ws;
  __hip_bfloat16* wih0p = (__hip_bfloat16*)(ws + OFF_WIH0);
  __hip_bfloat16* whh0p = (__hip_bfloat16*)(ws + OFF_WHH0);
  __hip_bfloat16* wih1p = (__hip_bfloat16*)(ws + OFF_WIH1);
  __hip_bfloat16* whh1p = (__hip_bfloat16*)(ws + OFF_WHH1);
  __hip_bfloat16* xbfp  = (__hip_bfloat16*)(ws + OFF_XBF);
  unsigned* h0rp        = (unsigned*)(ws + OFF_H0R);
  unsigned* h1rp        = (unsigned*)(ws + OFF_H1R);
  unsigned* prgp        = (unsigned*)(ws + OFF_PRG);

  // zero tagged h slot buffers (tag 0 = initial state) + progress flags
  hipMemsetAsync(ws + OFF_H0R, 0, 2097152 * 2 + 1024, stream);

  // fp32 -> bf16 plain row-major copies
  cvt_bf16x4<<<2048,  256, 0, stream>>>((const float4*)Wih0, (ushort4*)wih0p, 2097152 / 4);
  cvt_bf16x4<<<4096,  256, 0, stream>>>((const float4*)Whh0, (ushort4*)whh0p, 4194304 / 4);
  cvt_bf16x4<<<4096,  256, 0, stream>>>((const float4*)Wih1, (ushort4*)wih1p, 4194304 / 4);
  cvt_bf16x4<<<4096,  256, 0, stream>>>((const float4*)Whh1, (ushort4*)whh1p, 4194304 / 4);
  cvt_bf16x4<<<16384, 256, 0, stream>>>((const float4*)x,    (ushort4*)xbfp, 16777216 / 4);

  void* args[] = { &whh0p, &wih0p, &wih1p, &whh1p, &xbfp, &h0rp, &h1rp, &prgp,
                   (void*)&b_ih0, (void*)&b_hh0, (void*)&b_ih1, (void*)&b_hh1,
                   &out };
  hipLaunchCooperativeKernel((const void*)lstm_persist, dim3(NBLK), dim3(NTHR),
                             args, 0, stream);
}